// Round 15
// baseline (1778.033 us; speedup 1.0000x reference)
//
#include <hip/hip_runtime.h>

// Weighted furthest point sampling + gathers for KeypointDetector.
// B=16, N=16384, C=128, S=1024, SEM=20.
//
// FPS: one 1024-thread block per batch. Hybrid point residency:
//   - points k=8..15 live in LDS as float4 [k-8][t] (128 KB): one
//     conflict-free ds_read_b128 per point = x,y,z,w in ONE issue slot;
//   - points k=0..7 + mind[16] live in registers (~48 floats, small enough
//     for the allocator to keep arch-resident).
// Per step: per-lane argmax over 16 points -> in-wave f32 max (DPP + 2
// shfls) -> leaders atomicMax(u32) into per-step LDS slot -> barrier ->
// score-matching threads atomicMin their index -> barrier.
// 32-bit reduce: value-max == bit-max since scores >= +0.
//
// Output layout (float*, concatenated in reference return order):
//   [0, 49152)                  sampled_xyz      [B,S,3]
//   [49152, 49152+2097152)      sample_seg_feat  [B,C,S]
//   [2146304, 2162688)          sample_seg_label [B,S] (stored as float)

#define FPS_B   16
#define FPS_N   16384
#define FPS_C   128
#define FPS_S   1024
#define FPS_SEM 20
#define FPS_T   1024
#define FPS_PPT 16   // points per thread = N / T
#define FPS_KR  8    // points kept in registers (k = 0..7)
#define FPS_KL  8    // points kept in LDS       (k = 8..15)

typedef unsigned long long ull;

// f32 lane permute via DPP (VALU-only). CTRL: 0xB1=xor1, 0x4E=xor2,
// 0x141=row_half_mirror (xor7 merge), 0x140=row_mirror (xor15 merge).
// Proven on HW in R10-R13 runs.
template <int CTRL>
__device__ __forceinline__ float dpp_movf(float v) {
  return __uint_as_float(__builtin_amdgcn_update_dpp(
      __float_as_uint(v), __float_as_uint(v), CTRL, 0xF, 0xF, true));
}

__global__ __launch_bounds__(FPS_T)
__attribute__((amdgpu_waves_per_eu(4, 4)))
void wfps_kernel(
    const float* __restrict__ xyz,    // [B,N,3]
    const int*   __restrict__ label,  // [B,N]
    int*         __restrict__ idx_out) // [B,S]
{
  const int b = blockIdx.x;
  const int t = threadIdx.x;
  const int lane = t & 63;

  __shared__ int counts[FPS_SEM];
  __shared__ float4 pts[FPS_KL][FPS_T];    // 128 KB: {x,y,z,w}, points k=8..15
  __shared__ unsigned wmax32[FPS_S];       // per-step max score bits (init 0)
  __shared__ int widx[FPS_S];              // per-step winner index (init MAX)

  if (t < FPS_SEM) counts[t] = 0;
  wmax32[t] = 0u;            // T == FPS_S: each thread inits one slot
  widx[t] = 0x7FFFFFFF;      // single-use slots: no per-step re-init
  __syncthreads();

  // ---- class-frequency weights ----
  const int* lab = label + b * FPS_N;
  int mylab[FPS_PPT];
#pragma unroll
  for (int k = 0; k < FPS_PPT; ++k) {
    mylab[k] = lab[t + k * FPS_T];
    atomicAdd(&counts[mylab[k]], 1);
  }
  __syncthreads();

  const float* xb = xyz + b * FPS_N * 3;

  // ---- points k=8..15 -> LDS float4 [k-8][t] ----
#pragma unroll
  for (int k = 0; k < FPS_KL; ++k) {
    int n = t + (k + FPS_KR) * FPS_T;
    float4 p;
    p.x = xb[n * 3 + 0];
    p.y = xb[n * 3 + 1];
    p.z = xb[n * 3 + 2];
    p.w = (float)counts[mylab[k + FPS_KR]];
    pts[k][t] = p;
  }

  // ---- points k=0..7 -> registers ----
  float px[FPS_KR], py[FPS_KR], pz[FPS_KR], w[FPS_KR];
#pragma unroll
  for (int k = 0; k < FPS_KR; ++k) {
    int n = t + k * FPS_T;
    px[k] = xb[n * 3 + 0];
    py[k] = xb[n * 3 + 1];
    pz[k] = xb[n * 3 + 2];
    w[k] = (float)counts[mylab[k]];
    asm("" : "+v"(px[k]), "+v"(py[k]), "+v"(pz[k]), "+v"(w[k]));
  }

  float mind[FPS_PPT];
#pragma unroll
  for (int k = 0; k < FPS_PPT; ++k) mind[k] = 1e10f;

  if (t == 0) idx_out[b * FPS_S] = 0;
  float lx = xb[0], ly = xb[1], lz = xb[2];
  __syncthreads();   // pts staged

  // ---- serial FPS loop ----
  for (int s = 1; s < FPS_S; ++s) {
    // local best over my 16 points (strict '>' keeps smallest k == smallest n)
    float bs = -1.0f;
    int bk = 0;
#pragma unroll
    for (int k = 0; k < FPS_KR; ++k) {   // register points (n = t + k*1024)
      // exact IEEE ops via _rn intrinsics: un-fusable, numpy summation order
      float dx = __fsub_rn(px[k], lx);
      float dy = __fsub_rn(py[k], ly);
      float dz = __fsub_rn(pz[k], lz);
      float d  = __fadd_rn(__fadd_rn(__fmul_rn(dx, dx), __fmul_rn(dy, dy)),
                           __fmul_rn(dz, dz));
      float m = fminf(mind[k], d);
      mind[k] = m;
      float sc = __fmul_rn(m, w[k]);
      bool g = sc > bs;
      bs = g ? sc : bs;
      bk = g ? k : bk;
    }
#pragma unroll
    for (int k = 0; k < FPS_KL; ++k) {   // LDS points (n = t + (k+8)*1024)
      float4 p = pts[k][t];              // one ds_read_b128, conflict-free
      float dx = __fsub_rn(p.x, lx);
      float dy = __fsub_rn(p.y, ly);
      float dz = __fsub_rn(p.z, lz);
      float d  = __fadd_rn(__fadd_rn(__fmul_rn(dx, dx), __fmul_rn(dy, dy)),
                           __fmul_rn(dz, dz));
      float m = fminf(mind[k + FPS_KR], d);
      mind[k + FPS_KR] = m;
      float sc = __fmul_rn(m, p.w);
      bool g = sc > bs;
      bs = g ? sc : bs;
      bk = g ? (k + FPS_KR) : bk;
    }

    // in-wave f32 max, value only: 4 DPP levels + 2 32-bit shfls.
    // scores >= +0 (w >= 1, d >= +0) so bit order == value order, no NaNs.
    float m = bs;
    m = fmaxf(m, dpp_movf<0xB1>(m));
    m = fmaxf(m, dpp_movf<0x4E>(m));
    m = fmaxf(m, dpp_movf<0x141>(m));
    m = fmaxf(m, dpp_movf<0x140>(m));
    m = fmaxf(m, __shfl_xor(m, 16, 64));
    m = fmaxf(m, __shfl_xor(m, 32, 64));

    if (lane == 0) atomicMax(&wmax32[s], __float_as_uint(m));
    __syncthreads();

    // phase 2: candidate threads (typically exactly one) race min-index
    unsigned M = wmax32[s];
    if (__float_as_uint(bs) == M)
      atomicMin(&widx[s], t + (bk << 10));
    __syncthreads();

    int cur = __builtin_amdgcn_readfirstlane(widx[s]);  // provably uniform
    if (t == 0) idx_out[b * FPS_S + s] = cur;

    // selected point coords: scalar/SMEM path (uniform address, cache-hot)
    const float* q = xb + 3 * cur;
    lx = q[0]; ly = q[1]; lz = q[2];
  }
}

// ---- gathers ----------------------------------------------------------------
__global__ void gather_kernel(
    const float* __restrict__ xyz,    // [B,N,3]
    const float* __restrict__ feat,   // [B,C,N]
    const int*   __restrict__ label,  // [B,N]
    const int*   __restrict__ idx,    // [B,S]
    float*       __restrict__ out)
{
  const long long FEAT = (long long)FPS_B * FPS_C * FPS_S;  // 2097152
  const int XYZN = FPS_B * FPS_S * 3;                       // 49152
  const int LABN = FPS_B * FPS_S;                           // 16384
  long long i = (long long)blockIdx.x * blockDim.x + threadIdx.x;

  if (i < FEAT) {
    int s = (int)(i & (FPS_S - 1));
    int c = (int)((i >> 10) & (FPS_C - 1));
    int b = (int)(i >> 17);
    int n = idx[b * FPS_S + s];
    out[XYZN + i] = feat[((long long)(b * FPS_C + c)) * FPS_N + n];
  } else if (i < FEAT + XYZN) {
    int j = (int)(i - FEAT);
    int d = j % 3;
    int sb = j / 3;
    int s = sb & (FPS_S - 1);
    int b = sb >> 10;
    int n = idx[b * FPS_S + s];
    out[j] = xyz[((long long)b * FPS_N + n) * 3 + d];
  } else if (i < FEAT + XYZN + LABN) {
    int j = (int)(i - FEAT - XYZN);
    int s = j & (FPS_S - 1);
    int b = j >> 10;
    int n = idx[b * FPS_S + s];
    out[FEAT + XYZN + j] = (float)label[b * FPS_N + n];
  }
}

extern "C" void kernel_launch(void* const* d_in, const int* in_sizes, int n_in,
                              void* d_out, int out_size, void* d_ws, size_t ws_size,
                              hipStream_t stream) {
  const float* xyz   = (const float*)d_in[0];
  const float* feat  = (const float*)d_in[1];
  const int*   label = (const int*)d_in[2];
  float* out = (float*)d_out;
  int*   idx = (int*)d_ws;  // B*S ints = 64 KiB scratch

  wfps_kernel<<<FPS_B, FPS_T, 0, stream>>>(xyz, label, idx);

  const long long total = (long long)FPS_B * FPS_C * FPS_S
                        + (long long)FPS_B * FPS_S * 3
                        + (long long)FPS_B * FPS_S;  // 2162688
  gather_kernel<<<(int)((total + 255) / 256), 256, 0, stream>>>(
      xyz, feat, label, idx, out);
}

// Round 16
// 1578.874 us; speedup vs baseline: 1.1261x; 1.1261x over previous
//
#include <hip/hip_runtime.h>

// Weighted furthest point sampling + gathers for KeypointDetector.
// B=16, N=16384, C=128, S=1024, SEM=20.
//
// FPS: one 1024-thread block per batch. Per step:
//   per-lane: update mind[k], track ONLY the max score bs (v_max, 1 inst/pt;
//   no in-loop index tracking) -> in-wave f32 max (4 DPP + 2 shfls) ->
//   wave leaders atomicMax(u32 score bits) into per-step LDS slot ->
//   barrier -> threads with bs==M re-scan mind[k]*w[k] (bit-exact register
//   recompute) for their smallest matching k and atomicMin(n) -> barrier.
// 32-bit everywhere: value-max == bit-max since scores >= +0.
// Tie-break == numpy argmax: smallest n among score-max candidates.
//
// Output layout (float*, concatenated in reference return order):
//   [0, 49152)                  sampled_xyz      [B,S,3]
//   [49152, 49152+2097152)      sample_seg_feat  [B,C,S]
//   [2146304, 2162688)          sample_seg_label [B,S] (stored as float)

#define FPS_B   16
#define FPS_N   16384
#define FPS_C   128
#define FPS_S   1024
#define FPS_SEM 20
#define FPS_T   1024
#define FPS_PPT 16   // points per thread = N / T

typedef unsigned long long ull;

// f32 lane permute via DPP (VALU-only). CTRL: 0xB1=xor1, 0x4E=xor2,
// 0x141=row_half_mirror (xor7 merge), 0x140=row_mirror (xor15 merge).
// Proven on HW in R10-R15 runs.
template <int CTRL>
__device__ __forceinline__ float dpp_movf(float v) {
  return __uint_as_float(__builtin_amdgcn_update_dpp(
      __float_as_uint(v), __float_as_uint(v), CTRL, 0xF, 0xF, true));
}

__global__ __launch_bounds__(FPS_T)
__attribute__((amdgpu_waves_per_eu(4, 4)))
void wfps_kernel(
    const float* __restrict__ xyz,    // [B,N,3]
    const int*   __restrict__ label,  // [B,N]
    int*         __restrict__ idx_out) // [B,S]
{
  const int b = blockIdx.x;
  const int t = threadIdx.x;
  const int lane = t & 63;

  __shared__ int counts[FPS_SEM];
  __shared__ unsigned wmax32[FPS_S];  // per-step max score bits (init 0)
  __shared__ int widx[FPS_S];         // per-step winner index (init MAX)

  if (t < FPS_SEM) counts[t] = 0;
  wmax32[t] = 0u;            // T == FPS_S: each thread inits one slot
  widx[t] = 0x7FFFFFFF;      // single-use slots: no per-step re-init
  __syncthreads();

  // ---- class-frequency weights ----
  const int* lab = label + b * FPS_N;
  int mylab[FPS_PPT];
#pragma unroll
  for (int k = 0; k < FPS_PPT; ++k) {
    mylab[k] = lab[t + k * FPS_T];
    atomicAdd(&counts[mylab[k]], 1);
  }
  __syncthreads();

  // ---- my 16 points in registers; n = t + k*1024 ----
  const float* xb = xyz + b * FPS_N * 3;
  float px[FPS_PPT], py[FPS_PPT], pz[FPS_PPT], w[FPS_PPT], mind[FPS_PPT];
#pragma unroll
  for (int k = 0; k < FPS_PPT; ++k) {
    int n = t + k * FPS_T;
    px[k] = xb[n * 3 + 0];
    py[k] = xb[n * 3 + 1];
    pz[k] = xb[n * 3 + 2];
    w[k] = (float)counts[mylab[k]];
    mind[k] = 1e10f;
    asm("" : "+v"(px[k]), "+v"(py[k]), "+v"(pz[k]), "+v"(w[k]));
  }

  if (t == 0) idx_out[b * FPS_S] = 0;
  float lx = xb[0], ly = xb[1], lz = xb[2];

  // ---- serial FPS loop (unroll 2: halve loop-control overhead) ----
#pragma unroll 2
  for (int s = 1; s < FPS_S; ++s) {
    // per-lane: update mind, track max score ONLY (no index in hot loop)
    float bs = -1.0f;
#pragma unroll
    for (int k = 0; k < FPS_PPT; ++k) {
      // exact IEEE ops via _rn intrinsics: un-fusable, numpy summation order
      float dx = __fsub_rn(px[k], lx);
      float dy = __fsub_rn(py[k], ly);
      float dz = __fsub_rn(pz[k], lz);
      float d  = __fadd_rn(__fadd_rn(__fmul_rn(dx, dx), __fmul_rn(dy, dy)),
                           __fmul_rn(dz, dz));
      float m = fminf(mind[k], d);
      mind[k] = m;
      float sc = __fmul_rn(m, w[k]);
      bs = fmaxf(bs, sc);           // 1 inst/pt argmax-value tracking
    }

    // in-wave f32 max, value only: 4 DPP levels + 2 32-bit shfls.
    // scores >= +0 (w >= 1, d >= +0) so bit order == value order, no NaNs.
    float m = bs;
    m = fmaxf(m, dpp_movf<0xB1>(m));
    m = fmaxf(m, dpp_movf<0x4E>(m));
    m = fmaxf(m, dpp_movf<0x141>(m));
    m = fmaxf(m, dpp_movf<0x140>(m));
    m = fmaxf(m, __shfl_xor(m, 16, 64));
    m = fmaxf(m, __shfl_xor(m, 32, 64));

    if (lane == 0) atomicMax(&wmax32[s], __float_as_uint(m));
    __syncthreads();

    // phase 2: candidates (bs == global max) recover their smallest matching
    // k by bit-exact register recompute, then race min-index. Descending scan
    // with overwrite -> first (smallest) matching k. 1-2 threads per block.
    unsigned M = wmax32[s];
    if (__float_as_uint(bs) == M) {
      int bk = 0;
#pragma unroll
      for (int k = FPS_PPT - 1; k >= 0; --k)
        if (__float_as_uint(__fmul_rn(mind[k], w[k])) == M) bk = k;
      atomicMin(&widx[s], t + (bk << 10));
    }
    __syncthreads();

    int cur = __builtin_amdgcn_readfirstlane(widx[s]);  // provably uniform
    if (t == 0) idx_out[b * FPS_S + s] = cur;

    // selected point coords: scalar/SMEM path (uniform address, cache-hot)
    const float* q = xb + 3 * cur;
    lx = q[0]; ly = q[1]; lz = q[2];
  }
}

// ---- gathers ----------------------------------------------------------------
__global__ void gather_kernel(
    const float* __restrict__ xyz,    // [B,N,3]
    const float* __restrict__ feat,   // [B,C,N]
    const int*   __restrict__ label,  // [B,N]
    const int*   __restrict__ idx,    // [B,S]
    float*       __restrict__ out)
{
  const long long FEAT = (long long)FPS_B * FPS_C * FPS_S;  // 2097152
  const int XYZN = FPS_B * FPS_S * 3;                       // 49152
  const int LABN = FPS_B * FPS_S;                           // 16384
  long long i = (long long)blockIdx.x * blockDim.x + threadIdx.x;

  if (i < FEAT) {
    int s = (int)(i & (FPS_S - 1));
    int c = (int)((i >> 10) & (FPS_C - 1));
    int b = (int)(i >> 17);
    int n = idx[b * FPS_S + s];
    out[XYZN + i] = feat[((long long)(b * FPS_C + c)) * FPS_N + n];
  } else if (i < FEAT + XYZN) {
    int j = (int)(i - FEAT);
    int d = j % 3;
    int sb = j / 3;
    int s = sb & (FPS_S - 1);
    int b = sb >> 10;
    int n = idx[b * FPS_S + s];
    out[j] = xyz[((long long)b * FPS_N + n) * 3 + d];
  } else if (i < FEAT + XYZN + LABN) {
    int j = (int)(i - FEAT - XYZN);
    int s = j & (FPS_S - 1);
    int b = j >> 10;
    int n = idx[b * FPS_S + s];
    out[FEAT + XYZN + j] = (float)label[b * FPS_N + n];
  }
}

extern "C" void kernel_launch(void* const* d_in, const int* in_sizes, int n_in,
                              void* d_out, int out_size, void* d_ws, size_t ws_size,
                              hipStream_t stream) {
  const float* xyz   = (const float*)d_in[0];
  const float* feat  = (const float*)d_in[1];
  const int*   label = (const int*)d_in[2];
  float* out = (float*)d_out;
  int*   idx = (int*)d_ws;  // B*S ints = 64 KiB scratch

  wfps_kernel<<<FPS_B, FPS_T, 0, stream>>>(xyz, label, idx);

  const long long total = (long long)FPS_B * FPS_C * FPS_S
                        + (long long)FPS_B * FPS_S * 3
                        + (long long)FPS_B * FPS_S;  // 2162688
  gather_kernel<<<(int)((total + 255) / 256), 256, 0, stream>>>(
      xyz, feat, label, idx, out);
}